// Round 14
// baseline (336.388 us; speedup 1.0000x reference)
//
#include <hip/hip_runtime.h>

// ---------- bf16 helpers (raw ushort bit ops, RNE store) ----------
__device__ __forceinline__ float bf2f(unsigned short u) {
  union { unsigned int i; float f; } c; c.i = ((unsigned int)u) << 16; return c.f;
}
__device__ __forceinline__ unsigned short f2bf(float f) {
  union { float f; unsigned int i; } c; c.f = f;
  unsigned int x = c.i;
  return (unsigned short)((x + 0x7fffu + ((x >> 16) & 1u)) >> 16);
}
__device__ __forceinline__ float lo16(unsigned int w) { return bf2f((unsigned short)(w & 0xffffu)); }
__device__ __forceinline__ float hi16(unsigned int w) { return bf2f((unsigned short)(w >> 16)); }

#define DD 128
#define HH 64
#define CC 40
#define NBUCK 512         // radix buckets (2 finalize blocks per CU)
#define NCHUNK 256        // hist chunks
#define NSCAT 128         // scatter blocks (2 hist chunks each -> ~98B streams)
#define MAXNPB 256        // max nodes per bucket (N <= 131072 -> <= 256)
#define NR 4              // LDS atomic-contention replicas in hist
#define ECAP 6144         // LDS edge-cache capacity in bktB (24 KB)

using bf16x8 = __attribute__((ext_vector_type(8))) short;   // 8 bf16 (4 VGPRs)
using f32x4  = __attribute__((ext_vector_type(4))) float;   // 4 fp32 acc

// ---------- detect (blk 0) + prep_w (blks 1-2) + hist (blks 3..3+NCHUNK) ----------
// hist blocks sniff isI64 locally (16 KB read) -> no cross-block flag dependency.
__global__ __launch_bounds__(256) void detect_prepw_hist(
    const unsigned int* e32u, const unsigned int* x32, int* flags,
    const void* W1l, const void* W1r, const void* b1,
    const void* W2l, const void* W2r, const void* b2,
    unsigned short* Wb1, unsigned short* Wb2, float* b1f, float* b2f,
    const int* e32, int E, int N, unsigned mulM, int* histG) {
  __shared__ int cnt[NBUCK * NR];              // 8 KB, shared scratch for all roles
  int tid = threadIdx.x;
  int b = blockIdx.x;

  if (b == 0) {                                // ---- detect role ----
    unsigned int v = 0;
    for (int i = tid; i < 4096; i += 256) v |= e32u[2 * i + 1];
    int c2 = 0;
    for (int i = tid; i < 4096; i += 256) {
      unsigned int w = x32[i];
      unsigned int expo = (w >> 7) & 0xffu;
      unsigned short lo = (unsigned short)(w & 0xffffu);
      if (lo == 0 || (expo >= 100u && expo <= 133u)) c2++;
    }
    cnt[tid] = (int)v; cnt[256 + tid] = c2; __syncthreads();
    for (int s = 128; s > 0; s >>= 1) {
      if (tid < s) { cnt[tid] |= cnt[tid + s]; cnt[256 + tid] += cnt[256 + tid + s]; }
      __syncthreads();
    }
    if (tid == 0) {
      flags[0] = (cnt[0] == 0) ? 1 : 0;
      flags[1] = (cnt[256] < 2048) ? 1 : 0;
    }
    return;
  }

  if (b <= 2) {                                // ---- prep_w roles ----
    const unsigned int* w32 = (const unsigned int*)W1l;
    int c2 = 0;
    for (int i = tid; i < 4096; i += 256) {
      unsigned int w = w32[i];
      unsigned int expo = (w >> 7) & 0xffu;
      unsigned short lo = (unsigned short)(w & 0xffffu);
      if (lo == 0 || (expo >= 100u && expo <= 133u)) c2++;
    }
    cnt[tid] = c2; __syncthreads();
    for (int s = 128; s > 0; s >>= 1) {
      if (tid < s) cnt[tid] += cnt[tid + s];
      __syncthreads();
    }
    int isf = (cnt[0] < 2048) ? 1 : 0;
    auto rd = [&](const void* p, int i) -> float {
      return isf ? ((const float*)p)[i] : bf2f(((const unsigned short*)p)[i]);
    };
    if (b == 1) {
      for (int idx = tid; idx < 128 * 128; idx += 256) {
        int n = idx >> 7, k = idx & 127;
        float v = (n < HH) ? rd(W1l, k * HH + n) : rd(W1r, k * HH + (n - HH));
        Wb1[idx] = f2bf(v);
      }
    } else {
      for (int idx = tid; idx < 48 * 128; idx += 256) {
        int n = idx >> 7, k = idx & 127;
        float v = 0.f;
        if (n < CC) v = (k < HH) ? rd(W2l, k * CC + n) : rd(W2r, (k - HH) * CC + n);
        Wb2[idx] = f2bf(v);
      }
      if (tid < HH) b1f[tid] = rd(b1, tid);
      if (tid < CC) b2f[tid] = rd(b2, tid);
    }
    return;
  }

  // ---- hist role (chunk hb = b-3), local isI64 sniff ----
  int hb = b - 3;
  unsigned int v = 0;
  for (int i = tid; i < 4096; i += 256) v |= e32u[2 * i + 1];
  cnt[tid] = (int)v; __syncthreads();
  for (int s = 128; s > 0; s >>= 1) {
    if (tid < s) cnt[tid] |= cnt[tid + s];
    __syncthreads();
  }
  int isI64 = (cnt[0] == 0) ? 1 : 0;
  __syncthreads();
  for (int i = tid; i < NBUCK * NR; i += 256) cnt[i] = 0;
  __syncthreads();
  int rep = tid & (NR - 1);
  int chunk = (E + NCHUNK - 1) / NCHUNK;
  int e0 = hb * chunk, e1 = min(e0 + chunk, E);
  for (int i = e0 + tid; i < e1; i += 256) {
    int d = isI64 ? e32[2 * (E + i)] : e32[E + i];
    d = min(max(d, 0), N - 1);
    int bk = (int)__umulhi((unsigned)d, mulM);
    atomicAdd(&cnt[bk * NR + rep], 1);
  }
  __syncthreads();
  for (int i = tid; i < NBUCK; i += 256)
    histG[i * NCHUNK + hb] =
        cnt[i * NR] + cnt[i * NR + 1] + cnt[i * NR + 2] + cnt[i * NR + 3];
}

// ---------- scanA: per-bucket local exclusive scan over its NCHUNK counts ----------
__global__ __launch_bounds__(256) void scanA(const int* histG, int* ohist, int* bsum) {
  __shared__ int t[NCHUNK];
  int b = blockIdx.x, tid = threadIdx.x;
  int v = histG[b * NCHUNK + tid];
  t[tid] = v; __syncthreads();
  for (int st = 1; st < NCHUNK; st <<= 1) {
    int u = (tid >= st) ? t[tid - st] : 0;
    __syncthreads();
    t[tid] += u;
    __syncthreads();
  }
  ohist[b * NCHUNK + tid] = t[tid] - v;        // exclusive
  if (tid == NCHUNK - 1) bsum[b] = t[tid];
}

// ---------- scanB: exclusive scan of NBUCK bucket totals -> bbase ----------
__global__ __launch_bounds__(512) void scanB(const int* bsum, int* bbase,
                                             int* row_ptr, int N, int E) {
  __shared__ int t[NBUCK];
  int tid = threadIdx.x;
  int v = bsum[tid];
  t[tid] = v; __syncthreads();
  for (int st = 1; st < NBUCK; st <<= 1) {
    int u = (tid >= st) ? t[tid - st] : 0;
    __syncthreads();
    t[tid] += u;
    __syncthreads();
  }
  bbase[tid] = t[tid] - v;                     // exclusive
  if (tid == 0) { bbase[NBUCK] = E; row_ptr[N] = E; }
}

// ---------- hybrid: scatter PACKED edges (ld<<17 | src) ∥ transform1 (MFMA) ----------
// scatter: NSCAT blocks, each covers 2 hist chunks -> ~98B append streams/bucket.
// transform1: per-wave LDS-staged coalesced x tile (flat 4KB bf16), then MFMA.
__global__ __launch_bounds__(256) void scat_or_t1(
    const int* e32, int E, int N, const int* flags, int nodesPerB,
    unsigned mulM, const int* ohist, const int* bbase, unsigned* ebuf,
    const void* xraw, const unsigned short* Wb1, const float* b1f,
    unsigned short* t1, unsigned short* s1, int T1B) {
  __shared__ unsigned short shmem[8192];       // 16 KB: cur[512] (scatter) | xs (t1)
  int b = blockIdx.x;
  int tid = threadIdx.x;

  if (b < NSCAT) {                             // ---- scatter role ----
    int* cur = (int*)shmem;
    for (int i = tid; i < NBUCK; i += 256)
      cur[i] = ohist[i * NCHUNK + 2 * b] + bbase[i];
    __syncthreads();
    int isI64 = flags[0];
    int chunk = (E + NCHUNK - 1) / NCHUNK;
    int e0 = 2 * b * chunk, e1 = min(e0 + 2 * chunk, E);
    for (int i = e0 + tid; i < e1; i += 256) {
      int s, d;
      if (isI64) { s = e32[2 * i]; d = e32[2 * (E + i)]; }
      else       { s = e32[i];     d = e32[E + i]; }
      s = min(max(s, 0), N - 1);
      d = min(max(d, 0), N - 1);
      int bk = (int)__umulhi((unsigned)d, mulM);
      int ld = d - bk * nodesPerB;             // < 256
      int p = atomicAdd(&cur[bk], 1);
      ebuf[p] = ((unsigned)ld << 17) | (unsigned)s;
    }
    return;
  }

  // ---- transform1 role (MFMA, LDS-staged coalesced loads) ----
  int t = b - NSCAT;
  if (t >= T1B) return;
  int lane = tid & 63, wv = tid >> 6;
  int nb = t * 64 + wv * 16;                   // wave's first node
  int oc = lane & 15, kgrp = lane >> 4;
  unsigned short* xs = shmem + wv * 2048;      // [16 rows][128] bf16, flat

  if (flags[1]) {                              // fp32 input: coalesced float4 + cvt
    const float4* x4 = (const float4*)xraw;
#pragma unroll
    for (int j = 0; j < 8; j++) {
      int c = j * 64 + lane;                   // 16B chunk index (32/row)
      int node2 = min(nb + (c >> 5), N - 1);
      float4 v = x4[(size_t)node2 * 32 + (c & 31)];
      unsigned short* dst = &xs[c * 4];
      dst[0] = f2bf(v.x); dst[1] = f2bf(v.y);
      dst[2] = f2bf(v.z); dst[3] = f2bf(v.w);
    }
  } else {                                     // bf16 input: coalesced 16B copies
    const unsigned short* x16 = (const unsigned short*)xraw;
#pragma unroll
    for (int j = 0; j < 4; j++) {
      int c = j * 64 + lane;                   // 16B chunk index (16/row)
      int node2 = min(nb + (c >> 4), N - 1);
      *(bf16x8*)&xs[c * 8] = *(const bf16x8*)&x16[(size_t)node2 * 128 + (c & 15) * 8];
    }
  }

  f32x4 acc[8];
#pragma unroll
  for (int i = 0; i < 8; i++) acc[i] = (f32x4){0.f, 0.f, 0.f, 0.f};
#pragma unroll
  for (int kb = 0; kb < 4; kb++) {
    int k0 = kb * 32 + kgrp * 8;
    bf16x8 af = *(const bf16x8*)&xs[oc * 128 + k0];
#pragma unroll
    for (int nblk = 0; nblk < 8; nblk++) {
      bf16x8 bfr = *(const bf16x8*)&Wb1[(nblk * 16 + oc) * 128 + k0];
      acc[nblk] = __builtin_amdgcn_mfma_f32_16x16x32_bf16(af, bfr, acc[nblk], 0, 0, 0);
    }
  }

  int r0 = kgrp * 4;                           // D rows this lane holds
#pragma unroll
  for (int nblk = 0; nblk < 8; nblk++) {
    float bias = (nblk >= 4) ? b1f[(nblk - 4) * 16 + oc] : 0.f;
#pragma unroll
    for (int r = 0; r < 4; r++) {
      int nn = nb + r0 + r;
      if (nn < N) {
        if (nblk < 4)
          t1[(size_t)nn * HH + nblk * 16 + oc] = f2bf(acc[nblk][r]);
        else
          s1[(size_t)nn * HH + (nblk - 4) * 16 + oc] = f2bf(acc[nblk][r] + bias);
      }
    }
  }
}

// ---------- one segment gather (4 edge slots x 8 chunks) ----------
__device__ __forceinline__ void gather_seg(const uint4* t8, const int* col,
                                           int s0, int s1, int r, int c,
                                           float acc[8]) {
  for (int base = s0; base < s1; base += 4) {
    int i = base + r;
    bool g = (i < s1);
    int nb = g ? col[i] : 0;
    uint4 v = make_uint4(0, 0, 0, 0);
    if (g) v = t8[(size_t)nb * 8 + c];
    acc[0] += lo16(v.x); acc[1] += hi16(v.x);
    acc[2] += lo16(v.y); acc[3] += hi16(v.y);
    acc[4] += lo16(v.z); acc[5] += hi16(v.z);
    acc[6] += lo16(v.w); acc[7] += hi16(v.w);
  }
}

// ---------- bktB_agg1: counting sort by dst, then fused aggregate1 ----------
// Phase 1: sort bucket's edges -> col + row_ptr + invd (as before).
// Phase 2 (same block): h = relu(mean(t1[nbrs]) + s1) for own nodes;
//   row bounds from LDS (end = cnt[ln], start = end - degL[ln]) -> no
//   dependency on the NEXT bucket's row_ptr write.
__global__ __launch_bounds__(256) void bktB_agg1(
    const unsigned* ebuf, const int* bbase,
    int nodesPerB, int* row_ptr, float* invd, int* col, int N,
    const unsigned short* t1, const unsigned short* s1v, unsigned short* h) {
  __shared__ unsigned ecache[ECAP];            // 24 KB packed edges
  __shared__ int cnt[MAXNPB];                  // counters -> cursors (1 KB)
  __shared__ int degL[MAXNPB];                 // per-node degree (1 KB)
  __shared__ int sA[256];
  int b = blockIdx.x;
  int tid = threadIdx.x;
  int base_node = b * nodesPerB;
  int nn = min(nodesPerB, N - base_node);
  if (nn <= 0) return;
  int eb0 = bbase[b], eb1 = bbase[b + 1];
  int nE = eb1 - eb0;
  const unsigned* ee = ebuf + eb0;
  bool useL = (nE <= ECAP);
  for (int i = tid; i < nn; i += 256) cnt[i] = 0;
  __syncthreads();
  if (useL) {
    for (int i = tid; i < nE; i += 256) {
      unsigned v = ee[i];
      ecache[i] = v;
      atomicAdd(&cnt[v >> 17], 1);             // key = local dst
    }
  } else {
    for (int i = tid; i < nE; i += 256) atomicAdd(&cnt[ee[i] >> 17], 1);
  }
  __syncthreads();
  int deg = (tid < nn) ? cnt[tid] : 0;
  if (tid < nn) {
    invd[base_node + tid] = 1.0f / (float)max(deg, 1);
    degL[tid] = deg;
  }
  sA[tid] = deg;
  __syncthreads();
  for (int st = 1; st < 256; st <<= 1) {
    int t = (tid >= st) ? sA[tid - st] : 0;
    __syncthreads();
    sA[tid] += t;
    __syncthreads();
  }
  int run = eb0 + sA[tid] - deg;
  __syncthreads();
  if (tid < nn) {
    row_ptr[base_node + tid] = run;
    cnt[tid] = run;                            // absolute fill cursor
  }
  __syncthreads();
  if (useL) {
    for (int i = tid; i < nE; i += 256) {
      unsigned v = ecache[i];
      int p = atomicAdd(&cnt[v >> 17], 1);
      col[p] = (int)(v & 0x1FFFFu);
    }
  } else {
    for (int i = tid; i < nE; i += 256) {
      unsigned v = ee[i];
      int p = atomicAdd(&cnt[v >> 17], 1);
      col[p] = (int)(v & 0x1FFFFu);
    }
  }
  __syncthreads();                             // cursors final: cnt[ln] = row end

  // ---- fused aggregate1 over this bucket's nodes ----
  int lane = tid & 63, wv = tid >> 6;
  int ns = lane >> 5, r = (lane >> 3) & 3, c = lane & 7;
  const uint4* t8 = (const uint4*)t1;
  int rounds = (nn + 7) / 8;
  for (int rr = 0; rr < rounds; rr++) {
    int ln = rr * 8 + wv * 2 + ns;
    bool ok = (ln < nn);
    int s1e = ok ? cnt[ln] : 0;
    int s0 = ok ? (s1e - degL[ln]) : 0;
    float acc[8] = {0, 0, 0, 0, 0, 0, 0, 0};
    gather_seg(t8, col, s0, s1e, r, c, acc);
#pragma unroll
    for (int m = 8; m <= 16; m <<= 1)
#pragma unroll
      for (int i = 0; i < 8; i++) acc[i] += __shfl_xor(acc[i], m, 64);
    if (ok && r == 0) {
      int n = base_node + ln;
      float id = 1.0f / (float)max(degL[ln], 1);
      uint4 sv = ((const uint4*)s1v)[(size_t)n * 8 + c];
      float sb[8] = {lo16(sv.x), hi16(sv.x), lo16(sv.y), hi16(sv.y),
                     lo16(sv.z), hi16(sv.z), lo16(sv.w), hi16(sv.w)};
      unsigned int o[4];
#pragma unroll
      for (int i = 0; i < 4; i++) {
        float a0 = fmaxf(acc[2 * i] * id + sb[2 * i], 0.f);
        float a1 = fmaxf(acc[2 * i + 1] * id + sb[2 * i + 1], 0.f);
        o[i] = (unsigned int)f2bf(a0) | ((unsigned int)f2bf(a1) << 16);
      }
      ((uint4*)h)[(size_t)n * 8 + c] = make_uint4(o[0], o[1], o[2], o[3]);
    }
  }
}

// ---------- agg2f: aggh = mean(h[nbrs]) -> LDS; fused layer-2 MFMA + log_softmax ----------
// Block = 64 nodes, 4 waves x 16 nodes (2 per round x 8 rounds).
// LDS tile [64][33] u32 (bf16x2-packed aggh, padded stride -> conflict-free reads).
__global__ __launch_bounds__(256) void agg2f(const unsigned short* h,
                                             const int* row_ptr, const float* invd,
                                             const int* col,
                                             const unsigned short* Wb2,
                                             const float* b2f,
                                             float* out, int N) {
  __shared__ unsigned lds[64 * 33];            // 8.25 KB
  int tid = threadIdx.x, wv = tid >> 6, lane = tid & 63;
  int ns = lane >> 5, r = (lane >> 3) & 3, c = lane & 7;
  int nb = blockIdx.x * 64;
  const uint4* h8 = (const uint4*)h;

  for (int rr = 0; rr < 8; rr++) {
    int ln = wv * 16 + rr * 2 + ns;
    int n = nb + ln;
    float acc[8] = {0, 0, 0, 0, 0, 0, 0, 0};
    int s0 = 0, s1e = 0;
    if (n < N) { s0 = row_ptr[n]; s1e = row_ptr[n + 1]; }
    gather_seg(h8, col, s0, s1e, r, c, acc);
#pragma unroll
    for (int m = 8; m <= 16; m <<= 1)
#pragma unroll
      for (int i = 0; i < 8; i++) acc[i] += __shfl_xor(acc[i], m, 64);
    if (r == 0) {
      float id = (n < N) ? invd[n] : 0.f;
#pragma unroll
      for (int q = 0; q < 4; q++) {
        unsigned u = (unsigned)f2bf(acc[2 * q] * id) |
                     ((unsigned)f2bf(acc[2 * q + 1] * id) << 16);
        lds[ln * 33 + c * 4 + q] = u;
      }
    }
  }
  __syncthreads();

  // ---- fused final: [aggh(LDS) | h] @ Wb2 + b2 -> log_softmax ----
  int oc = lane & 15, kgrp = lane >> 4;
  int noderow = wv * 16 + oc;                  // block-local A row
  int node = min(nb + noderow, N - 1);
  f32x4 acc3[3];
#pragma unroll
  for (int i = 0; i < 3; i++) acc3[i] = (f32x4){0.f, 0.f, 0.f, 0.f};

#pragma unroll
  for (int kb = 0; kb < 4; kb++) {
    int k0 = kb * 32 + kgrp * 8;
    bf16x8 af;
    if (kb < 2) {                              // aggh from LDS (already bf16-packed)
      union { unsigned u[4]; bf16x8 v; } cv;
      int base = noderow * 33 + (k0 >> 1);
      cv.u[0] = lds[base]; cv.u[1] = lds[base + 1];
      cv.u[2] = lds[base + 2]; cv.u[3] = lds[base + 3];
      af = cv.v;
    } else {                                   // h from global (L2-warm)
      af = *(const bf16x8*)&h[(size_t)node * HH + (k0 - 64)];
    }
#pragma unroll
    for (int nblk = 0; nblk < 3; nblk++) {
      bf16x8 bfr = *(const bf16x8*)&Wb2[(nblk * 16 + oc) * 128 + k0];
      acc3[nblk] = __builtin_amdgcn_mfma_f32_16x16x32_bf16(af, bfr, acc3[nblk], 0, 0, 0);
    }
  }

#pragma unroll
  for (int nblk = 0; nblk < 3; nblk++) {
    int cc = nblk * 16 + oc;
    float bias = (cc < CC) ? b2f[cc] : 0.f;
#pragma unroll
    for (int rg = 0; rg < 4; rg++) acc3[nblk][rg] += bias;
  }

#pragma unroll
  for (int rg = 0; rg < 4; rg++) {
    int nn = nb + wv * 16 + kgrp * 4 + rg;
    float m = -INFINITY;
#pragma unroll
    for (int nblk = 0; nblk < 3; nblk++)
      if (nblk * 16 + oc < CC) m = fmaxf(m, acc3[nblk][rg]);
    for (int off = 1; off <= 8; off <<= 1) m = fmaxf(m, __shfl_xor(m, off, 64));
    float s = 0.f;
#pragma unroll
    for (int nblk = 0; nblk < 3; nblk++)
      if (nblk * 16 + oc < CC) s += __expf(acc3[nblk][rg] - m);
    for (int off = 1; off <= 8; off <<= 1) s += __shfl_xor(s, off, 64);
    float lse = m + __logf(s);
    if (nn < N) {
#pragma unroll
      for (int nblk = 0; nblk < 3; nblk++) {
        int cc = nblk * 16 + oc;
        if (cc < CC) out[(size_t)nn * CC + cc] = acc3[nblk][rg] - lse;
      }
    }
  }
}

extern "C" void kernel_launch(void* const* d_in, const int* in_sizes, int n_in,
                              void* d_out, int out_size, void* d_ws, size_t ws_size,
                              hipStream_t stream) {
  const void* x   = d_in[0];
  const int*  e   = (const int*)d_in[1];
  const void* W1l = d_in[2];
  const void* W1r = d_in[3];
  const void* b1  = d_in[4];
  const void* W2l = d_in[5];
  const void* W2r = d_in[6];
  const void* b2  = d_in[7];
  float* out = (float*)d_out;

  const int N = in_sizes[0] / DD;            // 100000
  const int E = in_sizes[1] / 2;             // 1600000
  const int nodesPerB = (N + NBUCK - 1) / NBUCK;   // 196
  const int nbuck = (N + nodesPerB - 1) / nodesPerB;
  const unsigned mulM =
      (unsigned)(((1ULL << 32) + (unsigned)nodesPerB - 1) / (unsigned)nodesPerB);
  const int T1B = (N + 63) / 64;             // 1563 (64 nodes per MFMA block)

  char* w = (char*)d_ws;
  size_t off = 0;
  auto carve = [&](size_t bytes) -> void* {
    void* p = (void*)(w + off);
    off += (bytes + 255) & ~(size_t)255;
    return p;
  };
  int* col      = (int*)carve((size_t)E * 4);
  int* row_ptr  = (int*)carve(((size_t)N + 1) * 4);
  float* invd   = (float*)carve((size_t)N * 4);
  int* histG    = (int*)carve((size_t)NBUCK * NCHUNK * 4);
  int* ohist    = (int*)carve((size_t)NBUCK * NCHUNK * 4);
  int* bsum     = (int*)carve(NBUCK * 4);
  int* bbase    = (int*)carve((NBUCK + 1) * 4);
  int* flags    = (int*)carve(8);
  unsigned short* t1   = (unsigned short*)carve((size_t)N * HH * 2);
  unsigned short* s1   = (unsigned short*)carve((size_t)N * HH * 2);
  unsigned short* h    = (unsigned short*)carve((size_t)N * HH * 2);
  unsigned short* Wb1  = (unsigned short*)carve(128 * 128 * 2);   // [n][k] bf16
  unsigned short* Wb2  = (unsigned short*)carve(48 * 128 * 2);    // [n][k] bf16
  float* b1f   = (float*)carve(HH * sizeof(float));
  float* b2f   = (float*)carve(CC * sizeof(float));
  unsigned* ebuf = (unsigned*)carve((size_t)E * 4);   // packed: ld<<17|src
  (void)ws_size; (void)n_in; (void)out_size;

  detect_prepw_hist<<<3 + NCHUNK, 256, 0, stream>>>(
      (const unsigned int*)e, (const unsigned int*)x, flags,
      W1l, W1r, b1, W2l, W2r, b2, Wb1, Wb2, b1f, b2f,
      e, E, N, mulM, histG);
  scanA<<<NBUCK, NCHUNK, 0, stream>>>(histG, ohist, bsum);
  scanB<<<1, 512, 0, stream>>>(bsum, bbase, row_ptr, N, E);
  scat_or_t1<<<NSCAT + T1B, 256, 0, stream>>>(e, E, N, flags, nodesPerB,
                                              mulM, ohist, bbase, ebuf,
                                              x, Wb1, b1f, t1, s1, T1B);
  bktB_agg1<<<nbuck, 256, 0, stream>>>(ebuf, bbase, nodesPerB, row_ptr, invd, col, N,
                                       t1, s1, h);
  agg2f<<<(N + 63) / 64, 256, 0, stream>>>(h, row_ptr, invd, col, Wb2, b2f, out, N);
}

// Round 15
// 273.974 us; speedup vs baseline: 1.2278x; 1.2278x over previous
//
#include <hip/hip_runtime.h>

// ---------- bf16 helpers (raw ushort bit ops, RNE store) ----------
__device__ __forceinline__ float bf2f(unsigned short u) {
  union { unsigned int i; float f; } c; c.i = ((unsigned int)u) << 16; return c.f;
}
__device__ __forceinline__ unsigned short f2bf(float f) {
  union { float f; unsigned int i; } c; c.f = f;
  unsigned int x = c.i;
  return (unsigned short)((x + 0x7fffu + ((x >> 16) & 1u)) >> 16);
}
__device__ __forceinline__ float lo16(unsigned int w) { return bf2f((unsigned short)(w & 0xffffu)); }
__device__ __forceinline__ float hi16(unsigned int w) { return bf2f((unsigned short)(w >> 16)); }

#define DD 128
#define HH 64
#define CC 40
#define NBUCK 512         // radix buckets (2 finalize blocks per CU)
#define NCHUNK 256        // hist chunks
#define NSCAT 128         // scatter blocks (2 hist chunks each -> ~98B streams)
#define MAXNPB 256        // max nodes per bucket (N <= 131072 -> <= 256)
#define NR 4              // LDS atomic-contention replicas in hist
#define ECAP 6144         // LDS edge-cache capacity in bktB (24 KB)

using bf16x8 = __attribute__((ext_vector_type(8))) short;   // 8 bf16 (4 VGPRs)
using f32x4  = __attribute__((ext_vector_type(4))) float;   // 4 fp32 acc

// ---------- detect (blk 0) + prep_w (blks 1-2) + hist (blks 3..3+NCHUNK) ----------
// hist blocks sniff isI64 locally (16 KB read) -> no cross-block flag dependency.
__global__ __launch_bounds__(256) void detect_prepw_hist(
    const unsigned int* e32u, const unsigned int* x32, int* flags,
    const void* W1l, const void* W1r, const void* b1,
    const void* W2l, const void* W2r, const void* b2,
    unsigned short* Wb1, unsigned short* Wb2, float* b1f, float* b2f,
    const int* e32, int E, int N, unsigned mulM, int* histG) {
  __shared__ int cnt[NBUCK * NR];              // 8 KB, shared scratch for all roles
  int tid = threadIdx.x;
  int b = blockIdx.x;

  if (b == 0) {                                // ---- detect role ----
    unsigned int v = 0;
    for (int i = tid; i < 4096; i += 256) v |= e32u[2 * i + 1];
    int c2 = 0;
    for (int i = tid; i < 4096; i += 256) {
      unsigned int w = x32[i];
      unsigned int expo = (w >> 7) & 0xffu;
      unsigned short lo = (unsigned short)(w & 0xffffu);
      if (lo == 0 || (expo >= 100u && expo <= 133u)) c2++;
    }
    cnt[tid] = (int)v; cnt[256 + tid] = c2; __syncthreads();
    for (int s = 128; s > 0; s >>= 1) {
      if (tid < s) { cnt[tid] |= cnt[tid + s]; cnt[256 + tid] += cnt[256 + tid + s]; }
      __syncthreads();
    }
    if (tid == 0) {
      flags[0] = (cnt[0] == 0) ? 1 : 0;
      flags[1] = (cnt[256] < 2048) ? 1 : 0;
    }
    return;
  }

  if (b <= 2) {                                // ---- prep_w roles ----
    const unsigned int* w32 = (const unsigned int*)W1l;
    int c2 = 0;
    for (int i = tid; i < 4096; i += 256) {
      unsigned int w = w32[i];
      unsigned int expo = (w >> 7) & 0xffu;
      unsigned short lo = (unsigned short)(w & 0xffffu);
      if (lo == 0 || (expo >= 100u && expo <= 133u)) c2++;
    }
    cnt[tid] = c2; __syncthreads();
    for (int s = 128; s > 0; s >>= 1) {
      if (tid < s) cnt[tid] += cnt[tid + s];
      __syncthreads();
    }
    int isf = (cnt[0] < 2048) ? 1 : 0;
    auto rd = [&](const void* p, int i) -> float {
      return isf ? ((const float*)p)[i] : bf2f(((const unsigned short*)p)[i]);
    };
    if (b == 1) {
      for (int idx = tid; idx < 128 * 128; idx += 256) {
        int n = idx >> 7, k = idx & 127;
        float v = (n < HH) ? rd(W1l, k * HH + n) : rd(W1r, k * HH + (n - HH));
        Wb1[idx] = f2bf(v);
      }
    } else {
      for (int idx = tid; idx < 48 * 128; idx += 256) {
        int n = idx >> 7, k = idx & 127;
        float v = 0.f;
        if (n < CC) v = (k < HH) ? rd(W2l, k * CC + n) : rd(W2r, (k - HH) * CC + n);
        Wb2[idx] = f2bf(v);
      }
      if (tid < HH) b1f[tid] = rd(b1, tid);
      if (tid < CC) b2f[tid] = rd(b2, tid);
    }
    return;
  }

  // ---- hist role (chunk hb = b-3), local isI64 sniff ----
  int hb = b - 3;
  unsigned int v = 0;
  for (int i = tid; i < 4096; i += 256) v |= e32u[2 * i + 1];
  cnt[tid] = (int)v; __syncthreads();
  for (int s = 128; s > 0; s >>= 1) {
    if (tid < s) cnt[tid] |= cnt[tid + s];
    __syncthreads();
  }
  int isI64 = (cnt[0] == 0) ? 1 : 0;
  __syncthreads();
  for (int i = tid; i < NBUCK * NR; i += 256) cnt[i] = 0;
  __syncthreads();
  int rep = tid & (NR - 1);
  int chunk = (E + NCHUNK - 1) / NCHUNK;
  int e0 = hb * chunk, e1 = min(e0 + chunk, E);
  for (int i = e0 + tid; i < e1; i += 256) {
    int d = isI64 ? e32[2 * (E + i)] : e32[E + i];
    d = min(max(d, 0), N - 1);
    int bk = (int)__umulhi((unsigned)d, mulM);
    atomicAdd(&cnt[bk * NR + rep], 1);
  }
  __syncthreads();
  for (int i = tid; i < NBUCK; i += 256)
    histG[i * NCHUNK + hb] =
        cnt[i * NR] + cnt[i * NR + 1] + cnt[i * NR + 2] + cnt[i * NR + 3];
}

// ---------- scanA: per-bucket local exclusive scan over its NCHUNK counts ----------
__global__ __launch_bounds__(256) void scanA(const int* histG, int* ohist, int* bsum) {
  __shared__ int t[NCHUNK];
  int b = blockIdx.x, tid = threadIdx.x;
  int v = histG[b * NCHUNK + tid];
  t[tid] = v; __syncthreads();
  for (int st = 1; st < NCHUNK; st <<= 1) {
    int u = (tid >= st) ? t[tid - st] : 0;
    __syncthreads();
    t[tid] += u;
    __syncthreads();
  }
  ohist[b * NCHUNK + tid] = t[tid] - v;        // exclusive
  if (tid == NCHUNK - 1) bsum[b] = t[tid];
}

// ---------- scanB: exclusive scan of NBUCK bucket totals -> bbase ----------
__global__ __launch_bounds__(512) void scanB(const int* bsum, int* bbase,
                                             int* row_ptr, int N, int E) {
  __shared__ int t[NBUCK];
  int tid = threadIdx.x;
  int v = bsum[tid];
  t[tid] = v; __syncthreads();
  for (int st = 1; st < NBUCK; st <<= 1) {
    int u = (tid >= st) ? t[tid - st] : 0;
    __syncthreads();
    t[tid] += u;
    __syncthreads();
  }
  bbase[tid] = t[tid] - v;                     // exclusive
  if (tid == 0) { bbase[NBUCK] = E; row_ptr[N] = E; }
}

// ---------- hybrid: scatter PACKED edges (ld<<17 | src) ∥ transform1 (MFMA) ----------
// scatter: NSCAT blocks, each covers 2 hist chunks -> ~98B append streams/bucket.
// transform1: per-wave LDS-staged coalesced x tile (flat 4KB bf16), then MFMA.
__global__ __launch_bounds__(256) void scat_or_t1(
    const int* e32, int E, int N, const int* flags, int nodesPerB,
    unsigned mulM, const int* ohist, const int* bbase, unsigned* ebuf,
    const void* xraw, const unsigned short* Wb1, const float* b1f,
    unsigned short* t1, unsigned short* s1, int T1B) {
  __shared__ unsigned short shmem[8192];       // 16 KB: cur[512] (scatter) | xs (t1)
  int b = blockIdx.x;
  int tid = threadIdx.x;

  if (b < NSCAT) {                             // ---- scatter role ----
    int* cur = (int*)shmem;
    for (int i = tid; i < NBUCK; i += 256)
      cur[i] = ohist[i * NCHUNK + 2 * b] + bbase[i];
    __syncthreads();
    int isI64 = flags[0];
    int chunk = (E + NCHUNK - 1) / NCHUNK;
    int e0 = 2 * b * chunk, e1 = min(e0 + 2 * chunk, E);
    for (int i = e0 + tid; i < e1; i += 256) {
      int s, d;
      if (isI64) { s = e32[2 * i]; d = e32[2 * (E + i)]; }
      else       { s = e32[i];     d = e32[E + i]; }
      s = min(max(s, 0), N - 1);
      d = min(max(d, 0), N - 1);
      int bk = (int)__umulhi((unsigned)d, mulM);
      int ld = d - bk * nodesPerB;             // < 256
      int p = atomicAdd(&cur[bk], 1);
      ebuf[p] = ((unsigned)ld << 17) | (unsigned)s;
    }
    return;
  }

  // ---- transform1 role (MFMA, LDS-staged coalesced loads) ----
  int t = b - NSCAT;
  if (t >= T1B) return;
  int lane = tid & 63, wv = tid >> 6;
  int nb = t * 64 + wv * 16;                   // wave's first node
  int oc = lane & 15, kgrp = lane >> 4;
  unsigned short* xs = shmem + wv * 2048;      // [16 rows][128] bf16, flat

  if (flags[1]) {                              // fp32 input: coalesced float4 + cvt
    const float4* x4 = (const float4*)xraw;
#pragma unroll
    for (int j = 0; j < 8; j++) {
      int c = j * 64 + lane;                   // 16B chunk index (32/row)
      int node2 = min(nb + (c >> 5), N - 1);
      float4 v = x4[(size_t)node2 * 32 + (c & 31)];
      unsigned short* dst = &xs[c * 4];
      dst[0] = f2bf(v.x); dst[1] = f2bf(v.y);
      dst[2] = f2bf(v.z); dst[3] = f2bf(v.w);
    }
  } else {                                     // bf16 input: coalesced 16B copies
    const unsigned short* x16 = (const unsigned short*)xraw;
#pragma unroll
    for (int j = 0; j < 4; j++) {
      int c = j * 64 + lane;                   // 16B chunk index (16/row)
      int node2 = min(nb + (c >> 4), N - 1);
      *(bf16x8*)&xs[c * 8] = *(const bf16x8*)&x16[(size_t)node2 * 128 + (c & 15) * 8];
    }
  }

  f32x4 acc[8];
#pragma unroll
  for (int i = 0; i < 8; i++) acc[i] = (f32x4){0.f, 0.f, 0.f, 0.f};
#pragma unroll
  for (int kb = 0; kb < 4; kb++) {
    int k0 = kb * 32 + kgrp * 8;
    bf16x8 af = *(const bf16x8*)&xs[oc * 128 + k0];
#pragma unroll
    for (int nblk = 0; nblk < 8; nblk++) {
      bf16x8 bfr = *(const bf16x8*)&Wb1[(nblk * 16 + oc) * 128 + k0];
      acc[nblk] = __builtin_amdgcn_mfma_f32_16x16x32_bf16(af, bfr, acc[nblk], 0, 0, 0);
    }
  }

  int r0 = kgrp * 4;                           // D rows this lane holds
#pragma unroll
  for (int nblk = 0; nblk < 8; nblk++) {
    float bias = (nblk >= 4) ? b1f[(nblk - 4) * 16 + oc] : 0.f;
#pragma unroll
    for (int r = 0; r < 4; r++) {
      int nn = nb + r0 + r;
      if (nn < N) {
        if (nblk < 4)
          t1[(size_t)nn * HH + nblk * 16 + oc] = f2bf(acc[nblk][r]);
        else
          s1[(size_t)nn * HH + (nblk - 4) * 16 + oc] = f2bf(acc[nblk][r] + bias);
      }
    }
  }
}

// ---------- bucketB: counting sort by dst; LDS edge cache ----------
__global__ __launch_bounds__(256) void bktB(
    const unsigned* ebuf, const int* bbase,
    int nodesPerB, int* row_ptr, float* invd, int* col, int N) {
  __shared__ unsigned ecache[ECAP];            // 24 KB packed edges
  __shared__ int cnt[MAXNPB];                  // key counters / cursors (1 KB)
  __shared__ int sA[256];
  int b = blockIdx.x;
  int tid = threadIdx.x;
  int base_node = b * nodesPerB;
  int nn = min(nodesPerB, N - base_node);
  if (nn <= 0) return;
  int eb0 = bbase[b], eb1 = bbase[b + 1];
  int nE = eb1 - eb0;
  const unsigned* ee = ebuf + eb0;
  bool useL = (nE <= ECAP);
  for (int i = tid; i < nn; i += 256) cnt[i] = 0;
  __syncthreads();
  if (useL) {
    for (int i = tid; i < nE; i += 256) {
      unsigned v = ee[i];
      ecache[i] = v;
      atomicAdd(&cnt[v >> 17], 1);             // key = local dst
    }
  } else {
    for (int i = tid; i < nE; i += 256) atomicAdd(&cnt[ee[i] >> 17], 1);
  }
  __syncthreads();
  int deg = (tid < nn) ? cnt[tid] : 0;
  if (tid < nn) invd[base_node + tid] = 1.0f / (float)max(deg, 1);
  sA[tid] = deg;
  __syncthreads();
  for (int st = 1; st < 256; st <<= 1) {
    int t = (tid >= st) ? sA[tid - st] : 0;
    __syncthreads();
    sA[tid] += t;
    __syncthreads();
  }
  int run = eb0 + sA[tid] - deg;
  __syncthreads();
  if (tid < nn) {
    row_ptr[base_node + tid] = run;
    cnt[tid] = run;                            // absolute fill cursor
  }
  __syncthreads();
  if (useL) {
    for (int i = tid; i < nE; i += 256) {
      unsigned v = ecache[i];
      int p = atomicAdd(&cnt[v >> 17], 1);
      col[p] = (int)(v & 0x1FFFFu);
    }
  } else {
    for (int i = tid; i < nE; i += 256) {
      unsigned v = ee[i];
      int p = atomicAdd(&cnt[v >> 17], 1);
      col[p] = (int)(v & 0x1FFFFu);
    }
  }
}

// ---------- one segment gather (4 edge slots x 8 chunks) ----------
__device__ __forceinline__ void gather_seg(const uint4* t8, const int* col,
                                           int s0, int s1, int r, int c,
                                           float acc[8]) {
  for (int base = s0; base < s1; base += 4) {
    int i = base + r;
    bool g = (i < s1);
    int nb = g ? col[i] : 0;
    uint4 v = make_uint4(0, 0, 0, 0);
    if (g) v = t8[(size_t)nb * 8 + c];
    acc[0] += lo16(v.x); acc[1] += hi16(v.x);
    acc[2] += lo16(v.y); acc[3] += hi16(v.y);
    acc[4] += lo16(v.z); acc[5] += hi16(v.z);
    acc[6] += lo16(v.w); acc[7] += hi16(v.w);
  }
}

// ---------- aggregate1: h = relu(mean(t1[nbrs]) + s1) ----------
// 2 nodes per wave: lane = ns(1b) | edge-slot r(2b) | chunk c(3b).
__global__ __launch_bounds__(256) void aggregate1(const unsigned short* t1,
                                                  const unsigned short* s1,
                                                  const int* row_ptr, const float* invd,
                                                  const int* col, unsigned short* h, int N) {
  int wave = threadIdx.x >> 6, lane = threadIdx.x & 63;
  int ns = lane >> 5, r = (lane >> 3) & 3, c = lane & 7;
  int n = blockIdx.x * 8 + wave * 2 + ns;
  if (n >= N) return;
  int s0 = row_ptr[n], s1e = row_ptr[n + 1];
  float acc[8] = {0, 0, 0, 0, 0, 0, 0, 0};
  gather_seg((const uint4*)t1, col, s0, s1e, r, c, acc);
#pragma unroll
  for (int m = 8; m <= 16; m <<= 1)
#pragma unroll
    for (int i = 0; i < 8; i++) acc[i] += __shfl_xor(acc[i], m, 64);

  if (r == 0) {
    float id = invd[n];
    uint4 sv = ((const uint4*)s1)[(size_t)n * 8 + c];
    float s[8] = {lo16(sv.x), hi16(sv.x), lo16(sv.y), hi16(sv.y),
                  lo16(sv.z), hi16(sv.z), lo16(sv.w), hi16(sv.w)};
    unsigned int o[4];
#pragma unroll
    for (int i = 0; i < 4; i++) {
      float a0 = fmaxf(acc[2 * i] * id + s[2 * i], 0.f);
      float a1 = fmaxf(acc[2 * i + 1] * id + s[2 * i + 1], 0.f);
      o[i] = (unsigned int)f2bf(a0) | ((unsigned int)f2bf(a1) << 16);
    }
    ((uint4*)h)[(size_t)n * 8 + c] = make_uint4(o[0], o[1], o[2], o[3]);
  }
}

// ---------- agg2f: aggh = mean(h[nbrs]) -> LDS; fused layer-2 MFMA + log_softmax ----------
// Block = 64 nodes, 4 waves x 16 nodes (2 per round x 8 rounds).
// LDS tile [64][33] u32 (bf16x2-packed aggh, padded stride -> conflict-free reads).
__global__ __launch_bounds__(256) void agg2f(const unsigned short* h,
                                             const int* row_ptr, const float* invd,
                                             const int* col,
                                             const unsigned short* Wb2,
                                             const float* b2f,
                                             float* out, int N) {
  __shared__ unsigned lds[64 * 33];            // 8.25 KB
  int tid = threadIdx.x, wv = tid >> 6, lane = tid & 63;
  int ns = lane >> 5, r = (lane >> 3) & 3, c = lane & 7;
  int nb = blockIdx.x * 64;
  const uint4* h8 = (const uint4*)h;

  for (int rr = 0; rr < 8; rr++) {
    int ln = wv * 16 + rr * 2 + ns;
    int n = nb + ln;
    float acc[8] = {0, 0, 0, 0, 0, 0, 0, 0};
    int s0 = 0, s1e = 0;
    if (n < N) { s0 = row_ptr[n]; s1e = row_ptr[n + 1]; }
    gather_seg(h8, col, s0, s1e, r, c, acc);
#pragma unroll
    for (int m = 8; m <= 16; m <<= 1)
#pragma unroll
      for (int i = 0; i < 8; i++) acc[i] += __shfl_xor(acc[i], m, 64);
    if (r == 0) {
      float id = (n < N) ? invd[n] : 0.f;
#pragma unroll
      for (int q = 0; q < 4; q++) {
        unsigned u = (unsigned)f2bf(acc[2 * q] * id) |
                     ((unsigned)f2bf(acc[2 * q + 1] * id) << 16);
        lds[ln * 33 + c * 4 + q] = u;
      }
    }
  }
  __syncthreads();

  // ---- fused final: [aggh(LDS) | h] @ Wb2 + b2 -> log_softmax ----
  int oc = lane & 15, kgrp = lane >> 4;
  int noderow = wv * 16 + oc;                  // block-local A row
  int node = min(nb + noderow, N - 1);
  f32x4 acc3[3];
#pragma unroll
  for (int i = 0; i < 3; i++) acc3[i] = (f32x4){0.f, 0.f, 0.f, 0.f};

#pragma unroll
  for (int kb = 0; kb < 4; kb++) {
    int k0 = kb * 32 + kgrp * 8;
    bf16x8 af;
    if (kb < 2) {                              // aggh from LDS (already bf16-packed)
      union { unsigned u[4]; bf16x8 v; } cv;
      int base = noderow * 33 + (k0 >> 1);
      cv.u[0] = lds[base]; cv.u[1] = lds[base + 1];
      cv.u[2] = lds[base + 2]; cv.u[3] = lds[base + 3];
      af = cv.v;
    } else {                                   // h from global (L2-warm)
      af = *(const bf16x8*)&h[(size_t)node * HH + (k0 - 64)];
    }
#pragma unroll
    for (int nblk = 0; nblk < 3; nblk++) {
      bf16x8 bfr = *(const bf16x8*)&Wb2[(nblk * 16 + oc) * 128 + k0];
      acc3[nblk] = __builtin_amdgcn_mfma_f32_16x16x32_bf16(af, bfr, acc3[nblk], 0, 0, 0);
    }
  }

#pragma unroll
  for (int nblk = 0; nblk < 3; nblk++) {
    int cc = nblk * 16 + oc;
    float bias = (cc < CC) ? b2f[cc] : 0.f;
#pragma unroll
    for (int rg = 0; rg < 4; rg++) acc3[nblk][rg] += bias;
  }

#pragma unroll
  for (int rg = 0; rg < 4; rg++) {
    int nn = nb + wv * 16 + kgrp * 4 + rg;
    float m = -INFINITY;
#pragma unroll
    for (int nblk = 0; nblk < 3; nblk++)
      if (nblk * 16 + oc < CC) m = fmaxf(m, acc3[nblk][rg]);
    for (int off = 1; off <= 8; off <<= 1) m = fmaxf(m, __shfl_xor(m, off, 64));
    float s = 0.f;
#pragma unroll
    for (int nblk = 0; nblk < 3; nblk++)
      if (nblk * 16 + oc < CC) s += __expf(acc3[nblk][rg] - m);
    for (int off = 1; off <= 8; off <<= 1) s += __shfl_xor(s, off, 64);
    float lse = m + __logf(s);
    if (nn < N) {
#pragma unroll
      for (int nblk = 0; nblk < 3; nblk++) {
        int cc = nblk * 16 + oc;
        if (cc < CC) out[(size_t)nn * CC + cc] = acc3[nblk][rg] - lse;
      }
    }
  }
}

extern "C" void kernel_launch(void* const* d_in, const int* in_sizes, int n_in,
                              void* d_out, int out_size, void* d_ws, size_t ws_size,
                              hipStream_t stream) {
  const void* x   = d_in[0];
  const int*  e   = (const int*)d_in[1];
  const void* W1l = d_in[2];
  const void* W1r = d_in[3];
  const void* b1  = d_in[4];
  const void* W2l = d_in[5];
  const void* W2r = d_in[6];
  const void* b2  = d_in[7];
  float* out = (float*)d_out;

  const int N = in_sizes[0] / DD;            // 100000
  const int E = in_sizes[1] / 2;             // 1600000
  const int nodesPerB = (N + NBUCK - 1) / NBUCK;   // 196
  const int nbuck = (N + nodesPerB - 1) / nodesPerB;
  const unsigned mulM =
      (unsigned)(((1ULL << 32) + (unsigned)nodesPerB - 1) / (unsigned)nodesPerB);
  const int T1B = (N + 63) / 64;             // 1563 (64 nodes per MFMA block)

  char* w = (char*)d_ws;
  size_t off = 0;
  auto carve = [&](size_t bytes) -> void* {
    void* p = (void*)(w + off);
    off += (bytes + 255) & ~(size_t)255;
    return p;
  };
  int* col      = (int*)carve((size_t)E * 4);
  int* row_ptr  = (int*)carve(((size_t)N + 1) * 4);
  float* invd   = (float*)carve((size_t)N * 4);
  int* histG    = (int*)carve((size_t)NBUCK * NCHUNK * 4);
  int* ohist    = (int*)carve((size_t)NBUCK * NCHUNK * 4);
  int* bsum     = (int*)carve(NBUCK * 4);
  int* bbase    = (int*)carve((NBUCK + 1) * 4);
  int* flags    = (int*)carve(8);
  unsigned short* t1   = (unsigned short*)carve((size_t)N * HH * 2);
  unsigned short* s1   = (unsigned short*)carve((size_t)N * HH * 2);
  unsigned short* h    = (unsigned short*)carve((size_t)N * HH * 2);
  unsigned short* Wb1  = (unsigned short*)carve(128 * 128 * 2);   // [n][k] bf16
  unsigned short* Wb2  = (unsigned short*)carve(48 * 128 * 2);    // [n][k] bf16
  float* b1f   = (float*)carve(HH * sizeof(float));
  float* b2f   = (float*)carve(CC * sizeof(float));
  unsigned* ebuf = (unsigned*)carve((size_t)E * 4);   // packed: ld<<17|src
  (void)ws_size; (void)n_in; (void)out_size;

  detect_prepw_hist<<<3 + NCHUNK, 256, 0, stream>>>(
      (const unsigned int*)e, (const unsigned int*)x, flags,
      W1l, W1r, b1, W2l, W2r, b2, Wb1, Wb2, b1f, b2f,
      e, E, N, mulM, histG);
  scanA<<<NBUCK, NCHUNK, 0, stream>>>(histG, ohist, bsum);
  scanB<<<1, 512, 0, stream>>>(bsum, bbase, row_ptr, N, E);
  scat_or_t1<<<NSCAT + T1B, 256, 0, stream>>>(e, E, N, flags, nodesPerB,
                                              mulM, ohist, bbase, ebuf,
                                              x, Wb1, b1f, t1, s1, T1B);
  bktB<<<nbuck, 256, 0, stream>>>(ebuf, bbase, nodesPerB, row_ptr, invd, col, N);
  aggregate1<<<(N + 7) / 8, 256, 0, stream>>>(t1, s1, row_ptr, invd, col, h, N);
  agg2f<<<(N + 63) / 64, 256, 0, stream>>>(h, row_ptr, invd, col, Wb2, b2f, out, N);
}